// Round 10
// baseline (233.043 us; speedup 1.0000x reference)
//
#include <hip/hip_runtime.h>
#include <stdint.h>

// SIREN batched MLP, MI355X/gfx950 — round 21: 32x32x16 MFMA restructure.
// r20 measured: 146.5 us, MfmaUtil 56 = VALUBusy 56 -> VALUBusy is mostly MFMA
// (v_mfma is VALU-class); pure VALU ~15%. Matrix pipe is the sole bottleneck,
// starved on ISSUE RATE (58% fed) not work. Fix: 32x32x16 MFMA halves the
// instruction count (328->172/tile) at ~2x pipe-occupancy per issue; ubench
// also 15% faster per FLOP (2382 vs 2075 TF).
// Key tricks:
//  (1) custom K-slot->feature map f(ks=2q+s, kl=8hi+e) = 32q+16s+4hi+8(e>>2)+(e&3)
//      chosen so layer-k acc rows land EXACTLY in layer-k+1 B-frag slots:
//      B[2q+s].e = sin(acc[q][8s+e]) — zero cross-lane ops in the epilogue.
//      (K-permutation is contraction-invariant; A and B use the same map.)
//  (2) L1 via MFMA: W1ext A-frag = [wxh,wxh,wxl,wyh,wyh,wyl,b1h,b1l] vs
//      B1 = [xh,xl,xh,yh,yl,yh,1,1] (hi=0 half; hi=1 zero) — exact split
//      products, f32 acc; deletes 48 LDS reads + 128 fmaf per tile.
// C/D 32x32 layout: col=lane&31, row=(r&3)+8*(r>>2)+4*(lane>>5) [m74/m101].
// Numerics: L2 3-term hi/lo, L3/L4/L5 hi-only, pkrtz epi (r20), omega folded,
// no v_fract, no cross-iter barrier. Expected absmax ~0.009-0.012 (<0.0167).
// Falsifier: absmax garbage -> A-frag lane-map wrong -> revert to r20.

typedef _Float16 f16x8 __attribute__((ext_vector_type(8)));
typedef __fp16 h16x2 __attribute__((ext_vector_type(2)));   // cvt_pkrtz return type
typedef float f32x4 __attribute__((ext_vector_type(4)));
typedef float f32x16 __attribute__((ext_vector_type(16)));

#define MFMA32(a, b, c) __builtin_amdgcn_mfma_f32_32x32x16_f16((a), (b), (c), 0, 0, 0)

#define B_ 32
#define N_ 32768
#define NTHR 1024
#define NWAVE 16
#define OMEGA_SC 4.77464829275686f   /* 30 / (2*pi) */

// flat param offsets (floats)
#define OFF_W1 0
#define OFF_B1 256
#define OFF_W2 384
#define OFF_B2 16768
#define OFF_W3 16896
#define OFF_B3 33280
#define OFF_W4 33408
#define OFF_B4 49792
#define OFF_W5 49920
#define OFF_B5 50304
#define NPARAM 50307

// LDS image offsets (bytes). Weight A-frag images: [ks(8)][mtA(4)][lane]*16B.
#define WO_L2H 0
#define WO_W2L 32768
#define WO_L3H 65536
#define WO_L4H 98304
#define WO_L5H 131072      /* 8 KB: [ks(8)][lane]*16B, rows 3..31 zero */
#define WO_W1E 139264      /* 4 KB: [mtA(4)][lane]*16B — W1ext split frags */
#define WO_BIA 143360      /* 3*128 f32, omega-scaled, canonical order */
#define LDSSET 144896

// args arrive pre-scaled by OMEGA_SC (revolutions); v_sin_f32 HW-reduces.
__device__ __forceinline__ float sin_rev(float t) {
    return __builtin_amdgcn_sinf(t);
}

__device__ __forceinline__ uint32_t pack2(_Float16 a, _Float16 b) {
    union { _Float16 h[2]; uint32_t u; } x;
    x.h[0] = a; x.h[1] = b;
    return x.u;
}

__device__ __forceinline__ uint32_t pkrtz_u32(float a, float b) {
    union { h16x2 v; uint32_t u; } x;
    x.v = __builtin_amdgcn_cvt_pkrtz(a, b);
    return x.u;
}

// sin pair -> hi/lo split packed via pkrtz (lo captures RTZ residual exactly)
__device__ __forceinline__ void sin_split_pk(float a0, float a1,
                                             uint32_t& hw, uint32_t& lw) {
    float s0 = sin_rev(a0), s1 = sin_rev(a1);
    union { h16x2 v; uint32_t u; } x, y;
    x.v = __builtin_amdgcn_cvt_pkrtz(s0, s1);
    float l0 = s0 - (float)x.v[0], l1 = s1 - (float)x.v[1];
    y.v = __builtin_amdgcn_cvt_pkrtz(l0, l1);
    hw = x.u; lw = y.u;
}

// ---------------------------------------------------------------------------
// Main: 1024 threads = 16 waves = 4 waves/SIMD, 1 block/CU (142 KB LDS).
// Geometry: per wave-tile 32 points (N=32, one col per lane), M=128 = 4
// m-tiles of 32, K=128 = 8 k-steps of 16. A-frag: lane holds
// A[m=32mtA+(l&31)][kl=8(l>>5)+e]; B-frag: B[kl][n=l&31]. Feature map:
// f(ks,kl) = 32(ks>>1) + 16(ks&1) + 4(kl>>3) + 8((kl&7)>>2) + ((kl&7)&3).
// Wave w takes tiles w, w+16, ... (8 each). Grid (32 batches, 8 slabs).
// ---------------------------------------------------------------------------
__global__ __launch_bounds__(NTHR, 4)
void siren_main(const float* __restrict__ xg,
                const float* __restrict__ pg,
                float* __restrict__ out) {
    extern __shared__ __align__(16) char smem[];

    const int t = threadIdx.x;
    const int b = blockIdx.x;
    const int grp = blockIdx.y;
    const float* p = pg + (size_t)b * NPARAM;

    // ---- fused prep: 114 u-slots x 64 lanes, wave-uniform u ----
    for (int it = t; it < 114 * 64; it += NTHR) {
        const int u = it >> 6, l = it & 63;
        if (u < 104) {
            // weight A-frag images (W2 hi+lo, W3, W4, W5)
            int li, ks, mtA;
            if (u < 96) { li = u >> 5; int r = u & 31; ks = r >> 2; mtA = r & 3; }
            else        { li = 3; ks = u - 96; mtA = 0; }
            const int mrow = l & 31, hi = l >> 5;
            const int q = ks >> 1, s = ks & 1;
            const int f0 = 32 * q + 16 * s + 4 * hi;
            int wOff; size_t dstH; bool lo = false;
            if (li == 0)      { wOff = OFF_W2; dstH = WO_L2H; lo = true; }
            else if (li == 1) { wOff = OFF_W3; dstH = WO_L3H; }
            else if (li == 2) { wOff = OFF_W4; dstH = WO_L4H; }
            else              { wOff = OFF_W5; dstH = WO_L5H; }
            const int j = 32 * mtA + mrow;
            const float sc = (li == 3) ? 1.0f : OMEGA_SC;

            float v[8];
            if (li == 3 && mrow >= 3) {
#pragma unroll
                for (int e = 0; e < 8; ++e) v[e] = 0.f;
            } else {
                float4 a  = *(const float4*)(p + wOff + j * 128 + f0);
                float4 bq = *(const float4*)(p + wOff + j * 128 + f0 + 8);
                v[0] = sc * a.x;  v[1] = sc * a.y;  v[2] = sc * a.z;  v[3] = sc * a.w;
                v[4] = sc * bq.x; v[5] = sc * bq.y; v[6] = sc * bq.z; v[7] = sc * bq.w;
            }
            f16x8 hv, lv;
#pragma unroll
            for (int e = 0; e < 8; ++e) {
                _Float16 hh = (_Float16)v[e];
                hv[e] = hh;
                lv[e] = (_Float16)(v[e] - (float)hh);
            }
            size_t idx = (li == 3) ? (size_t)(ks * 64 + l) * 16
                                   : (size_t)((ks * 4 + mtA) * 64 + l) * 16;
            *(f16x8*)(smem + dstH + idx) = hv;
            if (lo) *(f16x8*)(smem + WO_W2L + idx) = lv;
        } else if (u < 108) {
            // W1ext split frags: A = [wxh,wxh,wxl,wyh,wyh,wyl,b1h,b1l] (hi=0)
            const int mtA = u - 104;
            const int mrow = l & 31, hi = l >> 5;
            const int j = 32 * mtA + mrow;
            float wx = OMEGA_SC * p[OFF_W1 + 2 * j];
            float wy = OMEGA_SC * p[OFF_W1 + 2 * j + 1];
            float b1 = OMEGA_SC * p[OFF_B1 + j];
            _Float16 wxh = (_Float16)wx, wyh = (_Float16)wy, b1h = (_Float16)b1;
            _Float16 wxl = (_Float16)(wx - (float)wxh);
            _Float16 wyl = (_Float16)(wy - (float)wyh);
            _Float16 b1l = (_Float16)(b1 - (float)b1h);
            f16x8 hv;
            if (hi == 0) {
                hv[0] = wxh; hv[1] = wxh; hv[2] = wxl; hv[3] = wyh;
                hv[4] = wyh; hv[5] = wyl; hv[6] = b1h; hv[7] = b1l;
            } else {
#pragma unroll
                for (int e = 0; e < 8; ++e) hv[e] = (_Float16)0.f;
            }
            *(f16x8*)(smem + WO_W1E + (size_t)(mtA * 64 + l) * 16) = hv;
        } else {
            int s2 = ((u - 108) << 6) + l;     // 0..383
            int li = s2 >> 7, f = s2 & 127;
            ((float*)(smem + WO_BIA))[s2] =
                OMEGA_SC * p[(li == 0 ? OFF_B2 : li == 1 ? OFF_B3 : OFF_B4) + f];
        }
    }
    const float b5_0 = p[OFF_B5], b5_1 = p[OFF_B5 + 1], b5_2 = p[OFF_B5 + 2];
    __syncthreads();

    const int lane = t & 63;
    const int wv = t >> 6;          // 0..15
    const int n = lane & 31;
    const int hi = lane >> 5;
    const int lb = lane * 16;

    const char* L2Hp = smem + WO_L2H;
    const char* W2Lp = smem + WO_W2L;
    const char* L3Hp = smem + WO_L3H;
    const char* L4Hp = smem + WO_L4H;
    const char* L5Hp = smem + WO_L5H;
    const char* W1Ep = smem + WO_W1E;
    const float* sBf = (const float*)(smem + WO_BIA);

    union UF { f16x8 v; uint32_t w[4]; };

    // acc[mtA] init from bias (layer li): reg 4*bb+j = b[32mtA + 8bb + 4hi + j]
    auto initb = [&](f32x16 (&A)[4], int li) {
#pragma unroll
        for (int mtA = 0; mtA < 4; ++mtA)
#pragma unroll
            for (int bb = 0; bb < 4; ++bb) {
                f32x4 tv = *(const f32x4*)(sBf + li * 128 + 32 * mtA + 8 * bb + 4 * hi);
                A[mtA][4 * bb + 0] = tv[0]; A[mtA][4 * bb + 1] = tv[1];
                A[mtA][4 * bb + 2] = tv[2]; A[mtA][4 * bb + 3] = tv[3];
            }
    };

    // acc -> next-layer B-frags, hi-only RTZ-pack: X[2q+s].e = sin(A[q][8s+e])
    auto epi_hi = [&](const f32x16 (&A)[4], UF (&Xh)[8]) {
#pragma unroll
        for (int q = 0; q < 4; ++q)
#pragma unroll
            for (int s = 0; s < 2; ++s) {
                float sv[8];
#pragma unroll
                for (int j = 0; j < 8; ++j) sv[j] = sin_rev(A[q][8 * s + j]);
                UF& X = Xh[2 * q + s];
                X.w[0] = pkrtz_u32(sv[0], sv[1]);
                X.w[1] = pkrtz_u32(sv[2], sv[3]);
                X.w[2] = pkrtz_u32(sv[4], sv[5]);
                X.w[3] = pkrtz_u32(sv[6], sv[7]);
            }
    };

#pragma unroll 1
    for (int tile = wv; tile < 128; tile += NWAVE) {
        const int ptb = grp * 4096 + tile * 32;
        const float2 xy = ((const float2*)xg)[(size_t)b * N_ + ptb + n];

        // ---- B1 frag: [xh, xl, xh, yh, yl, yh, 1, 1] (hi=0), zeros (hi=1)
        UF B1;
        {
            _Float16 xh = (_Float16)xy.x, yh = (_Float16)xy.y;
            _Float16 xl = (_Float16)(xy.x - (float)xh);
            _Float16 yl = (_Float16)(xy.y - (float)yh);
            B1.w[0] = (hi == 0) ? pack2(xh, xl) : 0u;
            B1.w[1] = (hi == 0) ? pack2(xh, yh) : 0u;
            B1.w[2] = (hi == 0) ? pack2(yl, yh) : 0u;
            B1.w[3] = (hi == 0) ? 0x3C003C00u : 0u;   // (1.0h, 1.0h)
        }

        // ---- L1 (via MFMA) fused into L2 per q: acc1[q] -> X1 h/l -> 3-term
        f32x16 A2[4];
        initb(A2, 0);
#pragma unroll
        for (int q = 0; q < 4; ++q) {
            f16x8 a1 = *(const f16x8*)(W1Ep + (size_t)(q * 64 + lane) * 16);
            f32x16 c1;
#pragma unroll
            for (int i = 0; i < 16; ++i) c1[i] = 0.f;
            c1 = MFMA32(a1, B1.v, c1);
#pragma unroll
            for (int s = 0; s < 2; ++s) {
                UF X1h, X1l;
                sin_split_pk(c1[8 * s + 0], c1[8 * s + 1], X1h.w[0], X1l.w[0]);
                sin_split_pk(c1[8 * s + 2], c1[8 * s + 3], X1h.w[1], X1l.w[1]);
                sin_split_pk(c1[8 * s + 4], c1[8 * s + 5], X1h.w[2], X1l.w[2]);
                sin_split_pk(c1[8 * s + 6], c1[8 * s + 7], X1h.w[3], X1l.w[3]);
                const int ks = 2 * q + s;
                __builtin_amdgcn_s_setprio(1);
#pragma unroll
                for (int mtA = 0; mtA < 4; ++mtA) {
                    f16x8 ah = *(const f16x8*)(L2Hp + (size_t)((ks * 4 + mtA) * 64) * 16 + lb);
                    f16x8 al = *(const f16x8*)(W2Lp + (size_t)((ks * 4 + mtA) * 64) * 16 + lb);
                    A2[mtA] = MFMA32(ah, X1h.v, A2[mtA]);
                    A2[mtA] = MFMA32(ah, X1l.v, A2[mtA]);
                    A2[mtA] = MFMA32(al, X1h.v, A2[mtA]);
                }
                __builtin_amdgcn_s_setprio(0);
            }
        }

        // ---- L3
        UF X2h[8];
        epi_hi(A2, X2h);
        f32x16 A3[4];
        initb(A3, 1);
        __builtin_amdgcn_s_setprio(1);
#pragma unroll
        for (int ks = 0; ks < 8; ++ks)
#pragma unroll
            for (int mtA = 0; mtA < 4; ++mtA) {
                f16x8 ah = *(const f16x8*)(L3Hp + (size_t)((ks * 4 + mtA) * 64) * 16 + lb);
                A3[mtA] = MFMA32(ah, X2h[ks].v, A3[mtA]);
            }
        __builtin_amdgcn_s_setprio(0);

        // ---- L4
        UF X3h[8];
        epi_hi(A3, X3h);
        f32x16 A4[4];
        initb(A4, 2);
        __builtin_amdgcn_s_setprio(1);
#pragma unroll
        for (int ks = 0; ks < 8; ++ks)
#pragma unroll
            for (int mtA = 0; mtA < 4; ++mtA) {
                f16x8 ah = *(const f16x8*)(L4Hp + (size_t)((ks * 4 + mtA) * 64) * 16 + lb);
                A4[mtA] = MFMA32(ah, X3h[ks].v, A4[mtA]);
            }
        __builtin_amdgcn_s_setprio(0);

        // ---- L5: single 32-row m-tile (rows 3..31 zero), unscaled weights
        UF X4h[8];
        epi_hi(A4, X4h);
        f32x16 a5;
#pragma unroll
        for (int i = 0; i < 16; ++i) a5[i] = 0.f;
        __builtin_amdgcn_s_setprio(1);
#pragma unroll
        for (int ks = 0; ks < 8; ++ks) {
            f16x8 ah = *(const f16x8*)(L5Hp + (size_t)(ks * 64) * 16 + lb);
            a5 = MFMA32(ah, X4h[ks].v, a5);
        }
        __builtin_amdgcn_s_setprio(0);

        if (hi == 0) {   // rows 0..2 (regs 0..2) = outputs j=0..2 for point n
            size_t o = ((size_t)b * N_ + ptb + n) * 3;
            out[o]     = a5[0] + b5_0;
            out[o + 1] = a5[1] + b5_1;
            out[o + 2] = a5[2] + b5_2;
        }
    }
}

extern "C" void kernel_launch(void* const* d_in, const int* in_sizes, int n_in,
                              void* d_out, int out_size, void* d_ws, size_t ws_size,
                              hipStream_t stream) {
    (void)in_sizes; (void)n_in; (void)out_size; (void)d_ws; (void)ws_size;
    const float* x = (const float*)d_in[0];
    const float* p = (const float*)d_in[1];
    float* o = (float*)d_out;

    // Raise the dynamic-LDS cap exactly once (not per graph-capture pass).
    static bool attr_done = false;
    if (!attr_done) {
        (void)hipFuncSetAttribute(reinterpret_cast<const void*>(siren_main),
                                  hipFuncAttributeMaxDynamicSharedMemorySize, LDSSET);
        attr_done = true;
    }
    siren_main<<<dim3(32, 8), NTHR, LDSSET, stream>>>(x, p, o);
}

// Round 11
// 220.833 us; speedup vs baseline: 1.0553x; 1.0553x over previous
//
#include <hip/hip_runtime.h>
#include <stdint.h>

// SIREN batched MLP, MI355X/gfx950 — round 22: r21 + despill (zero-init acc,
// bias folded into epilogue).
// r21 measured: 180.5 us, absmax 0.0098 (32x32 layout math VERIFIED), but
// WRITE_SIZE 12288->44032 KB & FETCH 7.3->51.6 MB = ~31MB scratch spills.
// Diagnosis: f32x16 acc tuples + initb's hoisted LDS bias loads overlap
// A2(64)+X(32)+A3(64) liveness > 128-reg budget at 4 waves/SIMD.
// r22: accumulators zero-init (no load -> no hoist incentive, late birth);
// bias added in the epilogue as sin(acc + b) — same LDS loads, placed where
// the old acc is dying. No hand-scheduling of MFMA stream (r17 lesson).
// Numerics: bias enters end of f32 chain (not bit-identical; ~same absmax).
// Structure: 32x32x16 MFMA, K-perm f(ks,kl)=32q+16s+4hi+8(e>>2)+(e&3),
// L1 via MFMA (W1ext hi/lo split + b1 cols), L2 3-term, L3/4/5 hi-only pkrtz.
// Falsifier: WRITE_SIZE still ~44MB -> theory wrong -> revert to r20.

typedef _Float16 f16x8 __attribute__((ext_vector_type(8)));
typedef __fp16 h16x2 __attribute__((ext_vector_type(2)));   // cvt_pkrtz return type
typedef float f32x4 __attribute__((ext_vector_type(4)));
typedef float f32x16 __attribute__((ext_vector_type(16)));

#define MFMA32(a, b, c) __builtin_amdgcn_mfma_f32_32x32x16_f16((a), (b), (c), 0, 0, 0)

#define B_ 32
#define N_ 32768
#define NTHR 1024
#define NWAVE 16
#define OMEGA_SC 4.77464829275686f   /* 30 / (2*pi) */

// flat param offsets (floats)
#define OFF_W1 0
#define OFF_B1 256
#define OFF_W2 384
#define OFF_B2 16768
#define OFF_W3 16896
#define OFF_B3 33280
#define OFF_W4 33408
#define OFF_B4 49792
#define OFF_W5 49920
#define OFF_B5 50304
#define NPARAM 50307

// LDS image offsets (bytes). Weight A-frag images: [ks(8)][mtA(4)][lane]*16B.
#define WO_L2H 0
#define WO_W2L 32768
#define WO_L3H 65536
#define WO_L4H 98304
#define WO_L5H 131072      /* 8 KB: [ks(8)][lane]*16B, rows 3..31 zero */
#define WO_W1E 139264      /* 4 KB: [mtA(4)][lane]*16B — W1ext split frags */
#define WO_BIA 143360      /* 3*128 f32, omega-scaled, canonical order */
#define LDSSET 144896

// args arrive pre-scaled by OMEGA_SC (revolutions); v_sin_f32 HW-reduces.
__device__ __forceinline__ float sin_rev(float t) {
    return __builtin_amdgcn_sinf(t);
}

__device__ __forceinline__ uint32_t pack2(_Float16 a, _Float16 b) {
    union { _Float16 h[2]; uint32_t u; } x;
    x.h[0] = a; x.h[1] = b;
    return x.u;
}

__device__ __forceinline__ uint32_t pkrtz_u32(float a, float b) {
    union { h16x2 v; uint32_t u; } x;
    x.v = __builtin_amdgcn_cvt_pkrtz(a, b);
    return x.u;
}

// sin pair -> hi/lo split packed via pkrtz (lo captures RTZ residual exactly)
__device__ __forceinline__ void sin_split_pk(float a0, float a1,
                                             uint32_t& hw, uint32_t& lw) {
    float s0 = sin_rev(a0), s1 = sin_rev(a1);
    union { h16x2 v; uint32_t u; } x, y;
    x.v = __builtin_amdgcn_cvt_pkrtz(s0, s1);
    float l0 = s0 - (float)x.v[0], l1 = s1 - (float)x.v[1];
    y.v = __builtin_amdgcn_cvt_pkrtz(l0, l1);
    hw = x.u; lw = y.u;
}

// ---------------------------------------------------------------------------
// Main: 1024 threads = 16 waves = 4 waves/SIMD, 1 block/CU (142 KB LDS).
// Geometry: per wave-tile 32 points (one col per lane), M=128 = 4 m-tiles of
// 32, K=128 = 8 k-steps of 16. A-frag: lane holds A[m=32mtA+(l&31)][kl=8(l>>5)+e];
// B-frag: B[kl][n=l&31]. C/D: col=lane&31, row=(r&3)+8*(r>>2)+4*(lane>>5).
// Feature map: f(ks,kl) = 32(ks>>1)+16(ks&1)+4(kl>>3)+8((kl&7)>>2)+((kl&7)&3).
// Wave w takes tiles w, w+16, ... (8 each). Grid (32 batches, 8 slabs).
// ---------------------------------------------------------------------------
__global__ __launch_bounds__(NTHR, 4)
void siren_main(const float* __restrict__ xg,
                const float* __restrict__ pg,
                float* __restrict__ out) {
    extern __shared__ __align__(16) char smem[];

    const int t = threadIdx.x;
    const int b = blockIdx.x;
    const int grp = blockIdx.y;
    const float* p = pg + (size_t)b * NPARAM;

    // ---- fused prep: 114 u-slots x 64 lanes, wave-uniform u ----
    for (int it = t; it < 114 * 64; it += NTHR) {
        const int u = it >> 6, l = it & 63;
        if (u < 104) {
            // weight A-frag images (W2 hi+lo, W3, W4, W5)
            int li, ks, mtA;
            if (u < 96) { li = u >> 5; int r = u & 31; ks = r >> 2; mtA = r & 3; }
            else        { li = 3; ks = u - 96; mtA = 0; }
            const int mrow = l & 31, hi = l >> 5;
            const int q = ks >> 1, s = ks & 1;
            const int f0 = 32 * q + 16 * s + 4 * hi;
            int wOff; size_t dstH; bool lo = false;
            if (li == 0)      { wOff = OFF_W2; dstH = WO_L2H; lo = true; }
            else if (li == 1) { wOff = OFF_W3; dstH = WO_L3H; }
            else if (li == 2) { wOff = OFF_W4; dstH = WO_L4H; }
            else              { wOff = OFF_W5; dstH = WO_L5H; }
            const int j = 32 * mtA + mrow;
            const float sc = (li == 3) ? 1.0f : OMEGA_SC;

            float v[8];
            if (li == 3 && mrow >= 3) {
#pragma unroll
                for (int e = 0; e < 8; ++e) v[e] = 0.f;
            } else {
                float4 a  = *(const float4*)(p + wOff + j * 128 + f0);
                float4 bq = *(const float4*)(p + wOff + j * 128 + f0 + 8);
                v[0] = sc * a.x;  v[1] = sc * a.y;  v[2] = sc * a.z;  v[3] = sc * a.w;
                v[4] = sc * bq.x; v[5] = sc * bq.y; v[6] = sc * bq.z; v[7] = sc * bq.w;
            }
            f16x8 hv, lv;
#pragma unroll
            for (int e = 0; e < 8; ++e) {
                _Float16 hh = (_Float16)v[e];
                hv[e] = hh;
                lv[e] = (_Float16)(v[e] - (float)hh);
            }
            size_t idx = (li == 3) ? (size_t)(ks * 64 + l) * 16
                                   : (size_t)((ks * 4 + mtA) * 64 + l) * 16;
            *(f16x8*)(smem + dstH + idx) = hv;
            if (lo) *(f16x8*)(smem + WO_W2L + idx) = lv;
        } else if (u < 108) {
            // W1ext split frags: A = [wxh,wxh,wxl,wyh,wyh,wyl,b1h,b1l] (hi=0)
            const int mtA = u - 104;
            const int mrow = l & 31, hi = l >> 5;
            const int j = 32 * mtA + mrow;
            float wx = OMEGA_SC * p[OFF_W1 + 2 * j];
            float wy = OMEGA_SC * p[OFF_W1 + 2 * j + 1];
            float b1 = OMEGA_SC * p[OFF_B1 + j];
            _Float16 wxh = (_Float16)wx, wyh = (_Float16)wy, b1h = (_Float16)b1;
            _Float16 wxl = (_Float16)(wx - (float)wxh);
            _Float16 wyl = (_Float16)(wy - (float)wyh);
            _Float16 b1l = (_Float16)(b1 - (float)b1h);
            f16x8 hv;
            if (hi == 0) {
                hv[0] = wxh; hv[1] = wxh; hv[2] = wxl; hv[3] = wyh;
                hv[4] = wyh; hv[5] = wyl; hv[6] = b1h; hv[7] = b1l;
            } else {
#pragma unroll
                for (int e = 0; e < 8; ++e) hv[e] = (_Float16)0.f;
            }
            *(f16x8*)(smem + WO_W1E + (size_t)(mtA * 64 + l) * 16) = hv;
        } else {
            int s2 = ((u - 108) << 6) + l;     // 0..383
            int li = s2 >> 7, f = s2 & 127;
            ((float*)(smem + WO_BIA))[s2] =
                OMEGA_SC * p[(li == 0 ? OFF_B2 : li == 1 ? OFF_B3 : OFF_B4) + f];
        }
    }
    const float b5_0 = p[OFF_B5], b5_1 = p[OFF_B5 + 1], b5_2 = p[OFF_B5 + 2];
    __syncthreads();

    const int lane = t & 63;
    const int wv = t >> 6;          // 0..15
    const int n = lane & 31;
    const int hi = lane >> 5;
    const int lb = lane * 16;

    const char* L2Hp = smem + WO_L2H;
    const char* W2Lp = smem + WO_W2L;
    const char* L3Hp = smem + WO_L3H;
    const char* L4Hp = smem + WO_L4H;
    const char* L5Hp = smem + WO_L5H;
    const char* W1Ep = smem + WO_W1E;
    const float* sBf = (const float*)(smem + WO_BIA);

    union UF { f16x8 v; uint32_t w[4]; };

    // acc -> next-layer B-frags with bias-in-epi:
    // X[2q+s].e=j <- sin(A[q][8s+j] + b[32q+16s+4hi + (j<4 ? j : 8+(j&3))])
    auto epi_hib = [&](const f32x16 (&A)[4], int li, UF (&Xh)[8]) {
#pragma unroll
        for (int q = 0; q < 4; ++q)
#pragma unroll
            for (int s = 0; s < 2; ++s) {
                const int base = li * 128 + 32 * q + 16 * s + 4 * hi;
                f32x4 b0 = *(const f32x4*)(sBf + base);
                f32x4 b1q = *(const f32x4*)(sBf + base + 8);
                float sv[8];
#pragma unroll
                for (int j = 0; j < 4; ++j) {
                    sv[j]     = sin_rev(A[q][8 * s + j] + b0[j]);
                    sv[4 + j] = sin_rev(A[q][8 * s + 4 + j] + b1q[j]);
                }
                UF& X = Xh[2 * q + s];
                X.w[0] = pkrtz_u32(sv[0], sv[1]);
                X.w[1] = pkrtz_u32(sv[2], sv[3]);
                X.w[2] = pkrtz_u32(sv[4], sv[5]);
                X.w[3] = pkrtz_u32(sv[6], sv[7]);
            }
    };

#pragma unroll 1
    for (int tile = wv; tile < 128; tile += NWAVE) {
        const int ptb = grp * 4096 + tile * 32;
        const float2 xy = ((const float2*)xg)[(size_t)b * N_ + ptb + n];

        // ---- B1 frag: [xh, xl, xh, yh, yl, yh, 1, 1] (hi=0), zeros (hi=1)
        UF B1;
        {
            _Float16 xh = (_Float16)xy.x, yh = (_Float16)xy.y;
            _Float16 xl = (_Float16)(xy.x - (float)xh);
            _Float16 yl = (_Float16)(xy.y - (float)yh);
            B1.w[0] = (hi == 0) ? pack2(xh, xl) : 0u;
            B1.w[1] = (hi == 0) ? pack2(xh, yh) : 0u;
            B1.w[2] = (hi == 0) ? pack2(yl, yh) : 0u;
            B1.w[3] = (hi == 0) ? 0x3C003C00u : 0u;   // (1.0h, 1.0h)
        }

        // ---- L1 (via MFMA) fused into L2 per q: acc1[q] -> X1 h/l -> 3-term
        f32x16 A2[4];
#pragma unroll
        for (int mtA = 0; mtA < 4; ++mtA)
#pragma unroll
            for (int i = 0; i < 16; ++i) A2[mtA][i] = 0.f;
#pragma unroll
        for (int q = 0; q < 4; ++q) {
            f16x8 a1 = *(const f16x8*)(W1Ep + (size_t)(q * 64 + lane) * 16);
            f32x16 c1;
#pragma unroll
            for (int i = 0; i < 16; ++i) c1[i] = 0.f;
            c1 = MFMA32(a1, B1.v, c1);
#pragma unroll
            for (int s = 0; s < 2; ++s) {
                UF X1h, X1l;
                sin_split_pk(c1[8 * s + 0], c1[8 * s + 1], X1h.w[0], X1l.w[0]);
                sin_split_pk(c1[8 * s + 2], c1[8 * s + 3], X1h.w[1], X1l.w[1]);
                sin_split_pk(c1[8 * s + 4], c1[8 * s + 5], X1h.w[2], X1l.w[2]);
                sin_split_pk(c1[8 * s + 6], c1[8 * s + 7], X1h.w[3], X1l.w[3]);
                const int ks = 2 * q + s;
                __builtin_amdgcn_s_setprio(1);
#pragma unroll
                for (int mtA = 0; mtA < 4; ++mtA) {
                    f16x8 ah = *(const f16x8*)(L2Hp + (size_t)((ks * 4 + mtA) * 64) * 16 + lb);
                    f16x8 al = *(const f16x8*)(W2Lp + (size_t)((ks * 4 + mtA) * 64) * 16 + lb);
                    A2[mtA] = MFMA32(ah, X1h.v, A2[mtA]);
                    A2[mtA] = MFMA32(ah, X1l.v, A2[mtA]);
                    A2[mtA] = MFMA32(al, X1h.v, A2[mtA]);
                }
                __builtin_amdgcn_s_setprio(0);
            }
        }

        // ---- L3
        UF X2h[8];
        epi_hib(A2, 0, X2h);
        f32x16 A3[4];
#pragma unroll
        for (int mtA = 0; mtA < 4; ++mtA)
#pragma unroll
            for (int i = 0; i < 16; ++i) A3[mtA][i] = 0.f;
        __builtin_amdgcn_s_setprio(1);
#pragma unroll
        for (int ks = 0; ks < 8; ++ks)
#pragma unroll
            for (int mtA = 0; mtA < 4; ++mtA) {
                f16x8 ah = *(const f16x8*)(L3Hp + (size_t)((ks * 4 + mtA) * 64) * 16 + lb);
                A3[mtA] = MFMA32(ah, X2h[ks].v, A3[mtA]);
            }
        __builtin_amdgcn_s_setprio(0);

        // ---- L4
        UF X3h[8];
        epi_hib(A3, 1, X3h);
        f32x16 A4[4];
#pragma unroll
        for (int mtA = 0; mtA < 4; ++mtA)
#pragma unroll
            for (int i = 0; i < 16; ++i) A4[mtA][i] = 0.f;
        __builtin_amdgcn_s_setprio(1);
#pragma unroll
        for (int ks = 0; ks < 8; ++ks)
#pragma unroll
            for (int mtA = 0; mtA < 4; ++mtA) {
                f16x8 ah = *(const f16x8*)(L4Hp + (size_t)((ks * 4 + mtA) * 64) * 16 + lb);
                A4[mtA] = MFMA32(ah, X3h[ks].v, A4[mtA]);
            }
        __builtin_amdgcn_s_setprio(0);

        // ---- L5: single 32-row m-tile (rows 3..31 zero), unscaled weights
        UF X4h[8];
        epi_hib(A4, 2, X4h);
        f32x16 a5;
#pragma unroll
        for (int i = 0; i < 16; ++i) a5[i] = 0.f;
        __builtin_amdgcn_s_setprio(1);
#pragma unroll
        for (int ks = 0; ks < 8; ++ks) {
            f16x8 ah = *(const f16x8*)(L5Hp + (size_t)(ks * 64) * 16 + lb);
            a5 = MFMA32(ah, X4h[ks].v, a5);
        }
        __builtin_amdgcn_s_setprio(0);

        if (hi == 0) {   // rows 0..2 (regs 0..2) = outputs j=0..2 for point n
            size_t o = ((size_t)b * N_ + ptb + n) * 3;
            out[o]     = a5[0] + b5_0;
            out[o + 1] = a5[1] + b5_1;
            out[o + 2] = a5[2] + b5_2;
        }
    }
}

extern "C" void kernel_launch(void* const* d_in, const int* in_sizes, int n_in,
                              void* d_out, int out_size, void* d_ws, size_t ws_size,
                              hipStream_t stream) {
    (void)in_sizes; (void)n_in; (void)out_size; (void)d_ws; (void)ws_size;
    const float* x = (const float*)d_in[0];
    const float* p = (const float*)d_in[1];
    float* o = (float*)d_out;

    // Raise the dynamic-LDS cap exactly once (not per graph-capture pass).
    static bool attr_done = false;
    if (!attr_done) {
        (void)hipFuncSetAttribute(reinterpret_cast<const void*>(siren_main),
                                  hipFuncAttributeMaxDynamicSharedMemorySize, LDSSET);
        attr_done = true;
    }
    siren_main<<<dim3(32, 8), NTHR, LDSSET, stream>>>(x, p, o);
}

// Round 12
// 211.572 us; speedup vs baseline: 1.1015x; 1.0438x over previous
//
#include <hip/hip_runtime.h>
#include <stdint.h>

// SIREN batched MLP, MI355X/gfx950 — round 23: r20 exact + L5 reg-cache + xy prefetch.
// r22 post-mortem: despill WORKED (WRITE 44032->12288) but 32x32 still 168us vs
// r20's 146.5 -> latency granularity (32cyc/instr, 24-deep acc chains, 4-way ILP
// vs 16x16's 8 accs) + L1-MFMA->sin serial stall. 32x32 axis CLOSED.
// r23 returns to the verified-best r20 structure with two no-math-change cuts:
//  (1) L5 weight frags (tile-invariant, 4x16B=16 VGPR) cached in regs before the
//      tile loop — removes 4 LDS reads/tile + LDS latency from the L5 tail.
//  (2) next-tile xy prefetch — global loads issue a full tile early.
// absmax must be BIT-EXACT 0.009765625 (no arithmetic change vs r20).
// Numerics: L1 fp32+split, L2 3-term hi/lo, L3/L4/L5 hi-only, pkrtz epi,
// omega folded into staged W1..W4/b1..b4, no v_fract, no cross-iter barrier.

typedef _Float16 f16x8 __attribute__((ext_vector_type(8)));
typedef __fp16 h16x2 __attribute__((ext_vector_type(2)));   // cvt_pkrtz return type
typedef float f32x4 __attribute__((ext_vector_type(4)));

#define MFMA16 __builtin_amdgcn_mfma_f32_16x16x32_f16

#define B_ 32
#define N_ 32768
#define NTHR 1024
#define NWAVE 16
#define OMEGA_SC 4.77464829275686f   /* 30 / (2*pi) */

// flat param offsets (floats)
#define OFF_W1 0
#define OFF_B1 256
#define OFF_W2 384
#define OFF_B2 16768
#define OFF_W3 16896
#define OFF_B3 33280
#define OFF_W4 33408
#define OFF_B4 49792
#define OFF_W5 49920
#define OFF_B5 50304
#define NPARAM 50307

// LDS image offsets (bytes). A-frag images: [c][mt][lane]*16B.
#define WO_L2H 0
#define WO_W2L 32768
#define WO_L3H 65536
#define WO_L4H 98304
#define WO_L5H 131072      /* 4 KB: single M-tile, rows 3..15 zero */
#define WO_W1X 135168      /* 128 floats, slot-ordered s = c*32 + k_local */
#define WO_W1Y 135680
#define WO_B1S 136192
#define LDS_BIAS 136704    /* 3*128 floats */
#define LDSSET 138240

// args arrive pre-scaled by OMEGA_SC (revolutions); v_sin_f32 HW-reduces.
__device__ __forceinline__ float sin_rev(float t) {
    return __builtin_amdgcn_sinf(t);
}

__device__ __forceinline__ uint32_t pkrtz_u32(float a, float b) {
    union { h16x2 v; uint32_t u; } x;
    x.v = __builtin_amdgcn_cvt_pkrtz(a, b);
    return x.u;
}

// sin pair -> hi/lo split packed via pkrtz (lo captures RTZ residual exactly)
__device__ __forceinline__ void sin_split_pk(float a0, float a1,
                                             uint32_t& hw, uint32_t& lw) {
    float s0 = sin_rev(a0), s1 = sin_rev(a1);
    union { h16x2 v; uint32_t u; } x, y;
    x.v = __builtin_amdgcn_cvt_pkrtz(s0, s1);
    float l0 = s0 - (float)x.v[0], l1 = s1 - (float)x.v[1];
    y.v = __builtin_amdgcn_cvt_pkrtz(l0, l1);
    hw = x.u; lw = y.u;
}

// ---------------------------------------------------------------------------
// Main: 1024 threads = 16 waves = 4 waves/SIMD, 1 block/CU (135 KB LDS).
// Phase 0 (fused prep): build LDS weight images directly from p, pre-scaled
//   by OMEGA_SC for the sine layers (W1..W4, b1..b4); W5/b5 unscaled.
//   16x16x32 A-frag: lane l holds A[m=16mt+(l&15)][k_local=8*(l>>4)+e];
//   feature f = 16c + 64*(e>=4) + 4g + (e&3). W2 stored hi+lo; W3/4/5 hi only.
// Phase 1: block covers a 4096-pt slab = 128 32-pt tiles; wave w takes tiles
//   w, w+16, ... (8 tiles each). Grid (32 batches, 8 slabs).
// ---------------------------------------------------------------------------
__global__ __launch_bounds__(NTHR, 4)
void siren_main(const float* __restrict__ xg,
                const float* __restrict__ pg,
                float* __restrict__ out) {
    extern __shared__ __align__(16) char smem[];

    const int t = threadIdx.x;
    const int b = blockIdx.x;
    const int grp = blockIdx.y;
    const float* p = pg + (size_t)b * NPARAM;

    // ---- fused prep: 102 u-slots x 64 lanes = 6528 items, wave-uniform u ----
    for (int it = t; it < 6528; it += NTHR) {
        const int u = it >> 6, l = it & 63;
        if (u < 100) {
            int li, c, mt;
            if (u < 96) { li = u >> 5; int r = u & 31; c = r >> 3; mt = r & 7; }
            else        { li = 3; c = u - 96; mt = 0; }
            const int m = l & 15, gA = l >> 4;
            int wOff; size_t dstH; bool lo = false;
            if (li == 0)      { wOff = OFF_W2; dstH = WO_L2H; lo = true; }
            else if (li == 1) { wOff = OFF_W3; dstH = WO_L3H; }
            else if (li == 2) { wOff = OFF_W4; dstH = WO_L4H; }
            else              { wOff = OFF_W5; dstH = WO_L5H; }
            const int j = (li == 3) ? m : (16 * mt + m);
            const int f0 = 16 * c + 4 * gA;
            const float sc = (li == 3) ? 1.0f : OMEGA_SC;   // W5 feeds no sine

            float v[8];
            if (li == 3 && m >= 3) {
#pragma unroll
                for (int e = 0; e < 8; ++e) v[e] = 0.f;
            } else {
                float4 a  = *(const float4*)(p + wOff + j * 128 + f0);
                float4 bq = *(const float4*)(p + wOff + j * 128 + f0 + 64);
                v[0] = sc * a.x;  v[1] = sc * a.y;  v[2] = sc * a.z;  v[3] = sc * a.w;
                v[4] = sc * bq.x; v[5] = sc * bq.y; v[6] = sc * bq.z; v[7] = sc * bq.w;
            }
            f16x8 hv, lv;
#pragma unroll
            for (int e = 0; e < 8; ++e) {
                _Float16 hh = (_Float16)v[e];
                hv[e] = hh;
                lv[e] = (_Float16)(v[e] - (float)hh);
            }
            size_t idx = (li == 3) ? (size_t)(c * 64 + l) * 16
                                   : (size_t)((c * 8 + mt) * 64 + l) * 16;
            *(f16x8*)(smem + dstH + idx) = hv;
            if (lo) *(f16x8*)(smem + WO_W2L + idx) = lv;
        } else {
            int s = ((u - 100) << 6) + l;      // 0..127
            int c = s >> 5, k = s & 31, gq = k >> 3, e = k & 7;
            int f = 16 * c + ((e & 4) ? 64 : 0) + 4 * gq + (e & 3);
            ((float*)(smem + WO_W1X))[s] = OMEGA_SC * p[OFF_W1 + 2 * f];
            ((float*)(smem + WO_W1Y))[s] = OMEGA_SC * p[OFF_W1 + 2 * f + 1];
            ((float*)(smem + WO_B1S))[s] = OMEGA_SC * p[OFF_B1 + f];
        }
    }
    float* sB = (float*)(smem + LDS_BIAS);
    if (t < 384) {
        int li = t >> 7, f = t & 127;
        sB[t] = OMEGA_SC * p[(li == 0 ? OFF_B2 : li == 1 ? OFF_B3 : OFF_B4) + f];
    }
    const float b5_0 = p[OFF_B5], b5_1 = p[OFF_B5 + 1], b5_2 = p[OFF_B5 + 2];
    __syncthreads();

    const int lane = t & 63;
    const int wv = t >> 6;          // 0..15
    const int n = lane & 15;
    const int g = lane >> 4;
    const int lb = lane * 16;

    const char* L2Hp = smem + WO_L2H;
    const char* W2Lp = smem + WO_W2L;
    const char* L3Hp = smem + WO_L3H;
    const char* L4Hp = smem + WO_L4H;
    const char* L5Hp = smem + WO_L5H;
    const float* W1X = (const float*)(smem + WO_W1X);
    const float* W1Y = (const float*)(smem + WO_W1Y);
    const float* B1S = (const float*)(smem + WO_B1S);

    union UF { f16x8 v; uint32_t w[4]; };

    // r23: L5 weight frags are tile-invariant -> hold in registers (16 VGPRs).
    f16x8 l5f[4];
#pragma unroll
    for (int c = 0; c < 4; ++c)
        l5f[c] = *(const f16x8*)(L5Hp + c * 1024 + lb);

    auto initb2 = [&](f32x4 (&A)[2][8], int li) {
#pragma unroll
        for (int mt = 0; mt < 8; ++mt) {
            f32x4 bb = *(const f32x4*)&sB[li * 128 + 16 * mt + 4 * g];
            A[0][mt] = bb;
            A[1][mt] = bb;
        }
    };

    // acc -> B-frag chunk c = {tile c regs 0-3 (e0-3), tile c+4 regs 0-3 (e4-7)}
    // pair-convert+pack in ONE v_cvt_pkrtz_f16_f32 (r20)
    auto epi_hi2 = [&](const f32x4 (&A)[2][8], UF (&Xh)[2][4]) {
#pragma unroll
        for (int pp = 0; pp < 2; ++pp)
#pragma unroll
            for (int c = 0; c < 4; ++c) {
                float s[8];
#pragma unroll
                for (int r = 0; r < 4; ++r) {
                    s[r]     = sin_rev(A[pp][c][r]);
                    s[4 + r] = sin_rev(A[pp][c + 4][r]);
                }
                Xh[pp][c].w[0] = pkrtz_u32(s[0], s[1]);
                Xh[pp][c].w[1] = pkrtz_u32(s[2], s[3]);
                Xh[pp][c].w[2] = pkrtz_u32(s[4], s[5]);
                Xh[pp][c].w[3] = pkrtz_u32(s[6], s[7]);
            }
    };

    // r23: next-tile xy prefetch — loads issue a full tile ahead of use.
    const size_t xbase = (size_t)b * N_ + grp * 4096;
    float2 nxy0 = ((const float2*)xg)[xbase + wv * 32 + n];
    float2 nxy1 = ((const float2*)xg)[xbase + wv * 32 + 16 + n];

#pragma unroll 1
    for (int tile = wv; tile < 128; tile += NWAVE) {
        const int ptb = grp * 4096 + tile * 32;
        const float2 xy0 = nxy0;
        const float2 xy1 = nxy1;
        if (tile + NWAVE < 128) {
            nxy0 = ((const float2*)xg)[xbase + (tile + NWAVE) * 32 + n];
            nxy1 = ((const float2*)xg)[xbase + (tile + NWAVE) * 32 + 16 + n];
        }

        // ---- L1+L2 fused per c-chunk (r16): produce X1h/l[.][c], consume in
        //      L2 c-pass; L1(c+1) VALU interleaves with in-flight MFMA(c).
        f32x4 A2[2][8];
        initb2(A2, 0);
#pragma unroll
        for (int c = 0; c < 4; ++c) {
            UF X1h[2], X1l[2];
            {
                const int s0 = c * 32 + g * 8;
                float4 wxa = *(const float4*)(W1X + s0), wxb = *(const float4*)(W1X + s0 + 4);
                float4 wya = *(const float4*)(W1Y + s0), wyb = *(const float4*)(W1Y + s0 + 4);
                float4 bba = *(const float4*)(B1S + s0), bbb = *(const float4*)(B1S + s0 + 4);
                float wx[8] = {wxa.x, wxa.y, wxa.z, wxa.w, wxb.x, wxb.y, wxb.z, wxb.w};
                float wy[8] = {wya.x, wya.y, wya.z, wya.w, wyb.x, wyb.y, wyb.z, wyb.w};
                float bc[8] = {bba.x, bba.y, bba.z, bba.w, bbb.x, bbb.y, bbb.z, bbb.w};
#pragma unroll
                for (int pp = 0; pp < 2; ++pp) {
                    const float px = pp ? xy1.x : xy0.x;
                    const float py = pp ? xy1.y : xy0.y;
                    float a[8];
#pragma unroll
                    for (int e = 0; e < 8; ++e)
                        a[e] = fmaf(px, wx[e], fmaf(py, wy[e], bc[e]));
                    sin_split_pk(a[0], a[1], X1h[pp].w[0], X1l[pp].w[0]);
                    sin_split_pk(a[2], a[3], X1h[pp].w[1], X1l[pp].w[1]);
                    sin_split_pk(a[4], a[5], X1h[pp].w[2], X1l[pp].w[2]);
                    sin_split_pk(a[6], a[7], X1h[pp].w[3], X1l[pp].w[3]);
                }
            }
            __builtin_amdgcn_s_setprio(1);
#pragma unroll
            for (int mt = 0; mt < 8; ++mt) {
                f16x8 ah = *(const f16x8*)(L2Hp + (c * 8 + mt) * 1024 + lb);
                f16x8 al = *(const f16x8*)(W2Lp + (c * 8 + mt) * 1024 + lb);
#pragma unroll
                for (int pp = 0; pp < 2; ++pp) {
                    A2[pp][mt] = MFMA16(ah, X1h[pp].v, A2[pp][mt], 0, 0, 0);
                    A2[pp][mt] = MFMA16(ah, X1l[pp].v, A2[pp][mt], 0, 0, 0);
                    A2[pp][mt] = MFMA16(al, X1h[pp].v, A2[pp][mt], 0, 0, 0);
                }
            }
            __builtin_amdgcn_s_setprio(0);
        }

        UF X2h[2][4];
        epi_hi2(A2, X2h);

        // ---- L3: 1-term (X2 hi only)
        f32x4 A3[2][8];
        initb2(A3, 1);
        __builtin_amdgcn_s_setprio(1);
#pragma unroll
        for (int c = 0; c < 4; ++c)
#pragma unroll
            for (int mt = 0; mt < 8; ++mt) {
                f16x8 ah = *(const f16x8*)(L3Hp + (c * 8 + mt) * 1024 + lb);
#pragma unroll
                for (int pp = 0; pp < 2; ++pp)
                    A3[pp][mt] = MFMA16(ah, X2h[pp][c].v, A3[pp][mt], 0, 0, 0);
            }
        __builtin_amdgcn_s_setprio(0);

        UF X3h[2][4];
        epi_hi2(A3, X3h);

        // ---- L4: plain f16
        f32x4 A4[2][8];
        initb2(A4, 2);
        __builtin_amdgcn_s_setprio(1);
#pragma unroll
        for (int c = 0; c < 4; ++c)
#pragma unroll
            for (int mt = 0; mt < 8; ++mt) {
                f16x8 ah = *(const f16x8*)(L4Hp + (c * 8 + mt) * 1024 + lb);
#pragma unroll
                for (int pp = 0; pp < 2; ++pp)
                    A4[pp][mt] = MFMA16(ah, X3h[pp][c].v, A4[pp][mt], 0, 0, 0);
            }
        __builtin_amdgcn_s_setprio(0);

        UF X4h[2][4];
        epi_hi2(A4, X4h);

        // ---- L5: single M-padded tile per point-tile (reg-cached frags)
        f32x4 a5[2] = {{0.f, 0.f, 0.f, 0.f}, {0.f, 0.f, 0.f, 0.f}};
        __builtin_amdgcn_s_setprio(1);
#pragma unroll
        for (int c = 0; c < 4; ++c) {
#pragma unroll
            for (int pp = 0; pp < 2; ++pp)
                a5[pp] = MFMA16(l5f[c], X4h[pp][c].v, a5[pp], 0, 0, 0);
        }
        __builtin_amdgcn_s_setprio(0);

        if (g == 0) {   // rows 0..2 = outputs j=0..2 for point n
#pragma unroll
            for (int pp = 0; pp < 2; ++pp) {
                size_t o = ((size_t)b * N_ + ptb + pp * 16 + n) * 3;
                out[o]     = a5[pp][0] + b5_0;
                out[o + 1] = a5[pp][1] + b5_1;
                out[o + 2] = a5[pp][2] + b5_2;
            }
        }
    }
}

extern "C" void kernel_launch(void* const* d_in, const int* in_sizes, int n_in,
                              void* d_out, int out_size, void* d_ws, size_t ws_size,
                              hipStream_t stream) {
    (void)in_sizes; (void)n_in; (void)out_size; (void)d_ws; (void)ws_size;
    const float* x = (const float*)d_in[0];
    const float* p = (const float*)d_in[1];
    float* o = (float*)d_out;

    // Raise the dynamic-LDS cap exactly once (not per graph-capture pass).
    static bool attr_done = false;
    if (!attr_done) {
        (void)hipFuncSetAttribute(reinterpret_cast<const void*>(siren_main),
                                  hipFuncAttributeMaxDynamicSharedMemorySize, LDSSET);
        attr_done = true;
    }
    siren_main<<<dim3(32, 8), NTHR, LDSSET, stream>>>(x, p, o);
}

// Round 13
// 205.584 us; speedup vs baseline: 1.1336x; 1.0291x over previous
//
#include <hip/hip_runtime.h>
#include <stdint.h>

// SIREN batched MLP, MI355X/gfx950 — round 24: restore exact r20 (verified best).
// r23 post-mortem: L5 reg-cache (16 contiguous VGPRs) + xy prefetch re-spilled
// (WRITE 12288->27709 KB, FETCH 7.3->14 MB) -> 160us. r20 sits ~15 regs from
// the 128-reg/4-wave cliff; ANY added loop-invariant register state spills.
// Session ledger: wins = 4 waves/SIMD, prep fusion, omega-fold, defract,
// debarrier, pkrtz epi (231.7 -> 146.5 us dispatch). Closed axes: hand-skew
// (r17), <3-term L2 numerics (r19: threshold 0.0167), 32x32 MFMA (r21/22:
// latency granularity), extra reg state (r23: spill cliff).
// This file is byte-equivalent to r20's kernel body.
// Numerics: L1 fp32+split, L2 3-term hi/lo, L3/L4/L5 hi-only, pkrtz epi,
// omega folded into staged W1..W4/b1..b4, no v_fract, no cross-iter barrier.
// Expected: dispatch ~146.5 us, absmax bit-exact 0.009765625.

typedef _Float16 f16x8 __attribute__((ext_vector_type(8)));
typedef __fp16 h16x2 __attribute__((ext_vector_type(2)));   // cvt_pkrtz return type
typedef float f32x4 __attribute__((ext_vector_type(4)));

#define MFMA16 __builtin_amdgcn_mfma_f32_16x16x32_f16

#define B_ 32
#define N_ 32768
#define NTHR 1024
#define NWAVE 16
#define OMEGA_SC 4.77464829275686f   /* 30 / (2*pi) */

// flat param offsets (floats)
#define OFF_W1 0
#define OFF_B1 256
#define OFF_W2 384
#define OFF_B2 16768
#define OFF_W3 16896
#define OFF_B3 33280
#define OFF_W4 33408
#define OFF_B4 49792
#define OFF_W5 49920
#define OFF_B5 50304
#define NPARAM 50307

// LDS image offsets (bytes). A-frag images: [c][mt][lane]*16B.
#define WO_L2H 0
#define WO_W2L 32768
#define WO_L3H 65536
#define WO_L4H 98304
#define WO_L5H 131072      /* 4 KB: single M-tile, rows 3..15 zero */
#define WO_W1X 135168      /* 128 floats, slot-ordered s = c*32 + k_local */
#define WO_W1Y 135680
#define WO_B1S 136192
#define LDS_BIAS 136704    /* 3*128 floats */
#define LDSSET 138240

// args arrive pre-scaled by OMEGA_SC (revolutions); v_sin_f32 HW-reduces.
__device__ __forceinline__ float sin_rev(float t) {
    return __builtin_amdgcn_sinf(t);
}

__device__ __forceinline__ uint32_t pkrtz_u32(float a, float b) {
    union { h16x2 v; uint32_t u; } x;
    x.v = __builtin_amdgcn_cvt_pkrtz(a, b);
    return x.u;
}

// sin pair -> hi/lo split packed via pkrtz (lo captures RTZ residual exactly)
__device__ __forceinline__ void sin_split_pk(float a0, float a1,
                                             uint32_t& hw, uint32_t& lw) {
    float s0 = sin_rev(a0), s1 = sin_rev(a1);
    union { h16x2 v; uint32_t u; } x, y;
    x.v = __builtin_amdgcn_cvt_pkrtz(s0, s1);
    float l0 = s0 - (float)x.v[0], l1 = s1 - (float)x.v[1];
    y.v = __builtin_amdgcn_cvt_pkrtz(l0, l1);
    hw = x.u; lw = y.u;
}

// ---------------------------------------------------------------------------
// Main: 1024 threads = 16 waves = 4 waves/SIMD, 1 block/CU (135 KB LDS).
// Phase 0 (fused prep): build LDS weight images directly from p, pre-scaled
//   by OMEGA_SC for the sine layers (W1..W4, b1..b4); W5/b5 unscaled.
//   16x16x32 A-frag: lane l holds A[m=16mt+(l&15)][k_local=8*(l>>4)+e];
//   feature f = 16c + 64*(e>=4) + 4g + (e&3). W2 stored hi+lo; W3/4/5 hi only.
// Phase 1: block covers a 4096-pt slab = 128 32-pt tiles; wave w takes tiles
//   w, w+16, ... (8 tiles each). Grid (32 batches, 8 slabs).
// ---------------------------------------------------------------------------
__global__ __launch_bounds__(NTHR, 4)
void siren_main(const float* __restrict__ xg,
                const float* __restrict__ pg,
                float* __restrict__ out) {
    extern __shared__ __align__(16) char smem[];

    const int t = threadIdx.x;
    const int b = blockIdx.x;
    const int grp = blockIdx.y;
    const float* p = pg + (size_t)b * NPARAM;

    // ---- fused prep: 102 u-slots x 64 lanes = 6528 items, wave-uniform u ----
    for (int it = t; it < 6528; it += NTHR) {
        const int u = it >> 6, l = it & 63;
        if (u < 100) {
            int li, c, mt;
            if (u < 96) { li = u >> 5; int r = u & 31; c = r >> 3; mt = r & 7; }
            else        { li = 3; c = u - 96; mt = 0; }
            const int m = l & 15, gA = l >> 4;
            int wOff; size_t dstH; bool lo = false;
            if (li == 0)      { wOff = OFF_W2; dstH = WO_L2H; lo = true; }
            else if (li == 1) { wOff = OFF_W3; dstH = WO_L3H; }
            else if (li == 2) { wOff = OFF_W4; dstH = WO_L4H; }
            else              { wOff = OFF_W5; dstH = WO_L5H; }
            const int j = (li == 3) ? m : (16 * mt + m);
            const int f0 = 16 * c + 4 * gA;
            const float sc = (li == 3) ? 1.0f : OMEGA_SC;   // W5 feeds no sine

            float v[8];
            if (li == 3 && m >= 3) {
#pragma unroll
                for (int e = 0; e < 8; ++e) v[e] = 0.f;
            } else {
                float4 a  = *(const float4*)(p + wOff + j * 128 + f0);
                float4 bq = *(const float4*)(p + wOff + j * 128 + f0 + 64);
                v[0] = sc * a.x;  v[1] = sc * a.y;  v[2] = sc * a.z;  v[3] = sc * a.w;
                v[4] = sc * bq.x; v[5] = sc * bq.y; v[6] = sc * bq.z; v[7] = sc * bq.w;
            }
            f16x8 hv, lv;
#pragma unroll
            for (int e = 0; e < 8; ++e) {
                _Float16 hh = (_Float16)v[e];
                hv[e] = hh;
                lv[e] = (_Float16)(v[e] - (float)hh);
            }
            size_t idx = (li == 3) ? (size_t)(c * 64 + l) * 16
                                   : (size_t)((c * 8 + mt) * 64 + l) * 16;
            *(f16x8*)(smem + dstH + idx) = hv;
            if (lo) *(f16x8*)(smem + WO_W2L + idx) = lv;
        } else {
            int s = ((u - 100) << 6) + l;      // 0..127
            int c = s >> 5, k = s & 31, gq = k >> 3, e = k & 7;
            int f = 16 * c + ((e & 4) ? 64 : 0) + 4 * gq + (e & 3);
            ((float*)(smem + WO_W1X))[s] = OMEGA_SC * p[OFF_W1 + 2 * f];
            ((float*)(smem + WO_W1Y))[s] = OMEGA_SC * p[OFF_W1 + 2 * f + 1];
            ((float*)(smem + WO_B1S))[s] = OMEGA_SC * p[OFF_B1 + f];
        }
    }
    float* sB = (float*)(smem + LDS_BIAS);
    if (t < 384) {
        int li = t >> 7, f = t & 127;
        sB[t] = OMEGA_SC * p[(li == 0 ? OFF_B2 : li == 1 ? OFF_B3 : OFF_B4) + f];
    }
    const float b5_0 = p[OFF_B5], b5_1 = p[OFF_B5 + 1], b5_2 = p[OFF_B5 + 2];
    __syncthreads();

    const int lane = t & 63;
    const int wv = t >> 6;          // 0..15
    const int n = lane & 15;
    const int g = lane >> 4;
    const int lb = lane * 16;

    const char* L2Hp = smem + WO_L2H;
    const char* W2Lp = smem + WO_W2L;
    const char* L3Hp = smem + WO_L3H;
    const char* L4Hp = smem + WO_L4H;
    const char* L5Hp = smem + WO_L5H;
    const float* W1X = (const float*)(smem + WO_W1X);
    const float* W1Y = (const float*)(smem + WO_W1Y);
    const float* B1S = (const float*)(smem + WO_B1S);

    union UF { f16x8 v; uint32_t w[4]; };

    auto initb2 = [&](f32x4 (&A)[2][8], int li) {
#pragma unroll
        for (int mt = 0; mt < 8; ++mt) {
            f32x4 bb = *(const f32x4*)&sB[li * 128 + 16 * mt + 4 * g];
            A[0][mt] = bb;
            A[1][mt] = bb;
        }
    };

    // acc -> B-frag chunk c = {tile c regs 0-3 (e0-3), tile c+4 regs 0-3 (e4-7)}
    // pair-convert+pack in ONE v_cvt_pkrtz_f16_f32 (RTZ)
    auto epi_hi2 = [&](const f32x4 (&A)[2][8], UF (&Xh)[2][4]) {
#pragma unroll
        for (int pp = 0; pp < 2; ++pp)
#pragma unroll
            for (int c = 0; c < 4; ++c) {
                float s[8];
#pragma unroll
                for (int r = 0; r < 4; ++r) {
                    s[r]     = sin_rev(A[pp][c][r]);
                    s[4 + r] = sin_rev(A[pp][c + 4][r]);
                }
                Xh[pp][c].w[0] = pkrtz_u32(s[0], s[1]);
                Xh[pp][c].w[1] = pkrtz_u32(s[2], s[3]);
                Xh[pp][c].w[2] = pkrtz_u32(s[4], s[5]);
                Xh[pp][c].w[3] = pkrtz_u32(s[6], s[7]);
            }
    };

#pragma unroll 1
    for (int tile = wv; tile < 128; tile += NWAVE) {
        const int ptb = grp * 4096 + tile * 32;
        const float2 xy0 = ((const float2*)xg)[(size_t)b * N_ + ptb + n];
        const float2 xy1 = ((const float2*)xg)[(size_t)b * N_ + ptb + 16 + n];

        // ---- L1+L2 fused per c-chunk (r16): produce X1h/l[.][c], consume in
        //      L2 c-pass; L1(c+1) VALU interleaves with in-flight MFMA(c).
        f32x4 A2[2][8];
        initb2(A2, 0);
#pragma unroll
        for (int c = 0; c < 4; ++c) {
            UF X1h[2], X1l[2];
            {
                const int s0 = c * 32 + g * 8;
                float4 wxa = *(const float4*)(W1X + s0), wxb = *(const float4*)(W1X + s0 + 4);
                float4 wya = *(const float4*)(W1Y + s0), wyb = *(const float4*)(W1Y + s0 + 4);
                float4 bba = *(const float4*)(B1S + s0), bbb = *(const float4*)(B1S + s0 + 4);
                float wx[8] = {wxa.x, wxa.y, wxa.z, wxa.w, wxb.x, wxb.y, wxb.z, wxb.w};
                float wy[8] = {wya.x, wya.y, wya.z, wya.w, wyb.x, wyb.y, wyb.z, wyb.w};
                float bc[8] = {bba.x, bba.y, bba.z, bba.w, bbb.x, bbb.y, bbb.z, bbb.w};
#pragma unroll
                for (int pp = 0; pp < 2; ++pp) {
                    const float px = pp ? xy1.x : xy0.x;
                    const float py = pp ? xy1.y : xy0.y;
                    float a[8];
#pragma unroll
                    for (int e = 0; e < 8; ++e)
                        a[e] = fmaf(px, wx[e], fmaf(py, wy[e], bc[e]));
                    sin_split_pk(a[0], a[1], X1h[pp].w[0], X1l[pp].w[0]);
                    sin_split_pk(a[2], a[3], X1h[pp].w[1], X1l[pp].w[1]);
                    sin_split_pk(a[4], a[5], X1h[pp].w[2], X1l[pp].w[2]);
                    sin_split_pk(a[6], a[7], X1h[pp].w[3], X1l[pp].w[3]);
                }
            }
            __builtin_amdgcn_s_setprio(1);
#pragma unroll
            for (int mt = 0; mt < 8; ++mt) {
                f16x8 ah = *(const f16x8*)(L2Hp + (c * 8 + mt) * 1024 + lb);
                f16x8 al = *(const f16x8*)(W2Lp + (c * 8 + mt) * 1024 + lb);
#pragma unroll
                for (int pp = 0; pp < 2; ++pp) {
                    A2[pp][mt] = MFMA16(ah, X1h[pp].v, A2[pp][mt], 0, 0, 0);
                    A2[pp][mt] = MFMA16(ah, X1l[pp].v, A2[pp][mt], 0, 0, 0);
                    A2[pp][mt] = MFMA16(al, X1h[pp].v, A2[pp][mt], 0, 0, 0);
                }
            }
            __builtin_amdgcn_s_setprio(0);
        }

        UF X2h[2][4];
        epi_hi2(A2, X2h);

        // ---- L3: 1-term (X2 hi only)
        f32x4 A3[2][8];
        initb2(A3, 1);
        __builtin_amdgcn_s_setprio(1);
#pragma unroll
        for (int c = 0; c < 4; ++c)
#pragma unroll
            for (int mt = 0; mt < 8; ++mt) {
                f16x8 ah = *(const f16x8*)(L3Hp + (c * 8 + mt) * 1024 + lb);
#pragma unroll
                for (int pp = 0; pp < 2; ++pp)
                    A3[pp][mt] = MFMA16(ah, X2h[pp][c].v, A3[pp][mt], 0, 0, 0);
            }
        __builtin_amdgcn_s_setprio(0);

        UF X3h[2][4];
        epi_hi2(A3, X3h);

        // ---- L4: plain f16
        f32x4 A4[2][8];
        initb2(A4, 2);
        __builtin_amdgcn_s_setprio(1);
#pragma unroll
        for (int c = 0; c < 4; ++c)
#pragma unroll
            for (int mt = 0; mt < 8; ++mt) {
                f16x8 ah = *(const f16x8*)(L4Hp + (c * 8 + mt) * 1024 + lb);
#pragma unroll
                for (int pp = 0; pp < 2; ++pp)
                    A4[pp][mt] = MFMA16(ah, X3h[pp][c].v, A4[pp][mt], 0, 0, 0);
            }
        __builtin_amdgcn_s_setprio(0);

        UF X4h[2][4];
        epi_hi2(A4, X4h);

        // ---- L5: single M-padded tile per point-tile (unscaled weights)
        f32x4 a5[2] = {{0.f, 0.f, 0.f, 0.f}, {0.f, 0.f, 0.f, 0.f}};
        __builtin_amdgcn_s_setprio(1);
#pragma unroll
        for (int c = 0; c < 4; ++c) {
            f16x8 ah = *(const f16x8*)(L5Hp + c * 1024 + lb);
#pragma unroll
            for (int pp = 0; pp < 2; ++pp)
                a5[pp] = MFMA16(ah, X4h[pp][c].v, a5[pp], 0, 0, 0);
        }
        __builtin_amdgcn_s_setprio(0);

        if (g == 0) {   // rows 0..2 = outputs j=0..2 for point n
#pragma unroll
            for (int pp = 0; pp < 2; ++pp) {
                size_t o = ((size_t)b * N_ + ptb + pp * 16 + n) * 3;
                out[o]     = a5[pp][0] + b5_0;
                out[o + 1] = a5[pp][1] + b5_1;
                out[o + 2] = a5[pp][2] + b5_2;
            }
        }
    }
}

extern "C" void kernel_launch(void* const* d_in, const int* in_sizes, int n_in,
                              void* d_out, int out_size, void* d_ws, size_t ws_size,
                              hipStream_t stream) {
    (void)in_sizes; (void)n_in; (void)out_size; (void)d_ws; (void)ws_size;
    const float* x = (const float*)d_in[0];
    const float* p = (const float*)d_in[1];
    float* o = (float*)d_out;

    // Raise the dynamic-LDS cap exactly once (not per graph-capture pass).
    static bool attr_done = false;
    if (!attr_done) {
        (void)hipFuncSetAttribute(reinterpret_cast<const void*>(siren_main),
                                  hipFuncAttributeMaxDynamicSharedMemorySize, LDSSET);
        attr_done = true;
    }
    siren_main<<<dim3(32, 8), NTHR, LDSSET, stream>>>(x, p, o);
}